// Round 12
// baseline (382.309 us; speedup 1.0000x reference)
//
#include <hip/hip_runtime.h>
#include <hip/hip_bf16.h>

// h_out[v] = sum over edges (u->v) of features[u]
// Counting-sort by 32-node dst-bucket, gather bf16-packed rows, LDS-acc,
// exclusive store. Edges split into halves A/B and software-pipelined:
//   histA | scanA | [k5A || histB] | [scanB + pack] | [k6A || k5B] | k6B(+=)
// so the sort/scatter phase hides under k6's random-read wall (~17.5
// cyc/edge/CU, invariant across 6 k6 variants in R5-R11).

#define NN     100000
#define FD     5
#define NOUTT  (NN * FD)      // 500000
#define NPS    32             // nodes per bucket
#define NPS_SH 5
#define NB     3125           // 100000 / 32 exactly
#define NSBH   400            // hist/scatter blocks per half (chunk = 8000)
#define BLK    256

typedef int vint4 __attribute__((ext_vector_type(4)));

__device__ __forceinline__ unsigned bf16rtn(float x) { // fp32 -> bf16 (RTN)
    unsigned u = __float_as_uint(x);
    u += 0x7fffu + ((u >> 16) & 1u);
    return u >> 16;
}
__device__ __forceinline__ float lo16(unsigned v) { return __uint_as_float(v << 16); }
__device__ __forceinline__ float hi16(unsigned v) { return __uint_as_float(v & 0xffff0000u); }

// ---------------- device bodies (shared arrays passed from globals) ---------

__device__ __forceinline__ void k2_body(int bid, const int* __restrict__ dst,
                                        unsigned short* __restrict__ bh,
                                        int chunk, int* h) {
    for (int b = threadIdx.x; b < NB; b += BLK) h[b] = 0;
    __syncthreads();
    long long e0 = (long long)bid * chunk;
    const vint4* d4 = (const vint4*)(dst + e0);
    int n4 = chunk >> 2;
    int i = threadIdx.x;
    for (; i + 3 * BLK < n4; i += 4 * BLK) {
        vint4 d0 = __builtin_nontemporal_load(&d4[i]);
        vint4 d1 = __builtin_nontemporal_load(&d4[i + BLK]);
        vint4 d2 = __builtin_nontemporal_load(&d4[i + 2 * BLK]);
        vint4 d3 = __builtin_nontemporal_load(&d4[i + 3 * BLK]);
        __builtin_amdgcn_sched_barrier(0);
        atomicAdd(&h[d0[0] >> NPS_SH], 1); atomicAdd(&h[d0[1] >> NPS_SH], 1);
        atomicAdd(&h[d0[2] >> NPS_SH], 1); atomicAdd(&h[d0[3] >> NPS_SH], 1);
        atomicAdd(&h[d1[0] >> NPS_SH], 1); atomicAdd(&h[d1[1] >> NPS_SH], 1);
        atomicAdd(&h[d1[2] >> NPS_SH], 1); atomicAdd(&h[d1[3] >> NPS_SH], 1);
        atomicAdd(&h[d2[0] >> NPS_SH], 1); atomicAdd(&h[d2[1] >> NPS_SH], 1);
        atomicAdd(&h[d2[2] >> NPS_SH], 1); atomicAdd(&h[d2[3] >> NPS_SH], 1);
        atomicAdd(&h[d3[0] >> NPS_SH], 1); atomicAdd(&h[d3[1] >> NPS_SH], 1);
        atomicAdd(&h[d3[2] >> NPS_SH], 1); atomicAdd(&h[d3[3] >> NPS_SH], 1);
    }
    for (; i < n4; i += BLK) {
        vint4 d = __builtin_nontemporal_load(&d4[i]);
        atomicAdd(&h[d[0] >> NPS_SH], 1); atomicAdd(&h[d[1] >> NPS_SH], 1);
        atomicAdd(&h[d[2] >> NPS_SH], 1); atomicAdd(&h[d[3] >> NPS_SH], 1);
    }
    __syncthreads();
    unsigned short* row = bh + (size_t)bid * NB;
    for (int b = threadIdx.x; b < NB; b += BLK) row[b] = (unsigned short)h[b];
}

__device__ __forceinline__ void k5_body(int bid, const int* __restrict__ src,
                                        const int* __restrict__ dst,
                                        const unsigned short* __restrict__ bh,
                                        const int* __restrict__ bbase,
                                        int* __restrict__ bdata, int chunk,
                                        int* cur) {
    const unsigned short* row = bh + (size_t)bid * NB;
    for (int b = threadIdx.x; b < NB; b += BLK)
        cur[b] = bbase[b] + (int)row[b];
    __syncthreads();
    long long e0 = (long long)bid * chunk;
    const vint4* d4 = (const vint4*)(dst + e0);
    const vint4* s4 = (const vint4*)(src + e0);
    int n4 = chunk >> 2;
    int i = threadIdx.x;
    for (; i + 3 * BLK < n4; i += 4 * BLK) {
        vint4 d[4], s[4];
#pragma unroll
        for (int k = 0; k < 4; ++k) {
            d[k] = __builtin_nontemporal_load(&d4[i + k * BLK]);
            s[k] = __builtin_nontemporal_load(&s4[i + k * BLK]);
        }
        __builtin_amdgcn_sched_barrier(0);
#pragma unroll
        for (int k = 0; k < 4; ++k) {
#pragma unroll
            for (int j = 0; j < 4; ++j) {
                int vv = d[k][j];
                int uu = s[k][j];
                int b = vv >> NPS_SH;
                int off = atomicAdd(&cur[b], 1);
                bdata[off] = (uu << NPS_SH) | (vv & (NPS - 1));  // plain store
            }
        }
    }
    for (; i < n4; i += BLK) {
        vint4 d = __builtin_nontemporal_load(&d4[i]);
        vint4 s = __builtin_nontemporal_load(&s4[i]);
#pragma unroll
        for (int j = 0; j < 4; ++j) {
            int vv = d[j];
            int uu = s[j];
            int b = vv >> NPS_SH;
            int off = atomicAdd(&cur[b], 1);
            bdata[off] = (uu << NPS_SH) | (vv & (NPS - 1));
        }
    }
}

#define UNR 4
__device__ __forceinline__ void k6_body(int b, const int* __restrict__ bdata,
                                        const uint4* __restrict__ fp,
                                        const int* __restrict__ bbase,
                                        const int* __restrict__ btot,
                                        float* __restrict__ out, bool addm,
                                        float* acc) {
    int t = threadIdx.x;
    if (t < NPS * FD) acc[t] = 0.f;
    __syncthreads();
    int base = bbase[b];
    int n = btot[b];
    int i = t;
    for (; i + (UNR - 1) * BLK < n; i += UNR * BLK) {
        int   l[UNR];
        uint4 g[UNR];
#pragma unroll
        for (int k = 0; k < UNR; ++k) {
            int w = bdata[base + i + k * BLK];
            l[k] = w & (NPS - 1);
            g[k] = fp[w >> NPS_SH];
        }
        __builtin_amdgcn_sched_barrier(0);
#pragma unroll
        for (int k = 0; k < UNR; ++k) {
            float* p = acc + l[k] * FD;
            atomicAdd(&p[0], lo16(g[k].x));
            atomicAdd(&p[1], hi16(g[k].x));
            atomicAdd(&p[2], lo16(g[k].y));
            atomicAdd(&p[3], hi16(g[k].y));
            atomicAdd(&p[4], lo16(g[k].z));
        }
    }
    for (; i < n; i += BLK) {
        int w = bdata[base + i];
        int l = w & (NPS - 1);
        uint4 g = fp[w >> NPS_SH];
        float* p = acc + l * FD;
        atomicAdd(&p[0], lo16(g.x)); atomicAdd(&p[1], hi16(g.x));
        atomicAdd(&p[2], lo16(g.y)); atomicAdd(&p[3], hi16(g.y));
        atomicAdd(&p[4], lo16(g.z));
    }
    __syncthreads();
    if (t < NPS * FD) {
        size_t o = (size_t)b * NPS * FD + t;
        if (addm) out[o] += acc[t];     // exclusive owner; prior pass stored
        else      out[o] = acc[t];
    }
}

__device__ __forceinline__ void k4_body(const int* __restrict__ btot,
                                        int* __restrict__ bbase, int* s) {
#define VPT 13   // 13*256 = 3328 >= 3125
    int t = threadIdx.x;
    int v[VPT], sum = 0;
#pragma unroll
    for (int k = 0; k < VPT; ++k) {
        int i = VPT * t + k;
        v[k] = (i < NB) ? btot[i] : 0;
        sum += v[k];
    }
    s[t] = sum;
    __syncthreads();
    for (int off = 1; off < BLK; off <<= 1) {
        int u = (t >= off) ? s[t - off] : 0;
        __syncthreads();
        s[t] += u;
        __syncthreads();
    }
    int run = s[t] - sum;
#pragma unroll
    for (int k = 0; k < VPT; ++k) {
        int i = VPT * t + k;
        if (i < NB) bbase[i] = run;
        run += v[k];
    }
}

// ---------------- globals ---------------------------------------------------

__global__ __launch_bounds__(BLK) void g_k2(const int* __restrict__ dst,
                                            unsigned short* __restrict__ bh,
                                            int chunk) {
    __shared__ int h[NB];
    k2_body(blockIdx.x, dst, bh, chunk, h);
}

// per-bucket exclusive scan over the NSBH block-counts (guarded pairs)
__global__ __launch_bounds__(BLK) void g_k3(unsigned short* __restrict__ bh,
                                            int* __restrict__ btot) {
    __shared__ int s[BLK];
    int b = blockIdx.x, t = threadIdx.x;
    int r0 = 2 * t, r1 = 2 * t + 1;
    int v0 = (r0 < NSBH) ? (int)bh[(size_t)r0 * NB + b] : 0;
    int v1 = (r1 < NSBH) ? (int)bh[(size_t)r1 * NB + b] : 0;
    int pair = v0 + v1;
    s[t] = pair;
    __syncthreads();
    for (int off = 1; off < BLK; off <<= 1) {
        int v = (t >= off) ? s[t - off] : 0;
        __syncthreads();
        s[t] += v;
        __syncthreads();
    }
    int base = s[t] - pair;
    if (r0 < NSBH) bh[(size_t)r0 * NB + b] = (unsigned short)base;
    if (r1 < NSBH) bh[(size_t)r1 * NB + b] = (unsigned short)(base + v0);
    if (t == BLK - 1) btot[b] = s[t];
}

__global__ __launch_bounds__(BLK) void g_k4(const int* __restrict__ btot,
                                            int* __restrict__ bbase) {
    __shared__ int s[BLK];
    k4_body(btot, bbase, s);
}

// scan for half B fused with feature bf16-pack (independent work)
__global__ __launch_bounds__(BLK) void g_k4k1(const int* __restrict__ btot,
                                              int* __restrict__ bbase,
                                              const float* __restrict__ f,
                                              uint4* __restrict__ fp) {
    __shared__ int s[BLK];
    if (blockIdx.x == 0) {
        k4_body(btot, bbase, s);
    } else {
        int i = (blockIdx.x - 1) * BLK + threadIdx.x;
        if (i < NN) {
            const float* r = f + (long long)i * FD;
            unsigned w0 = bf16rtn(r[0]), w1 = bf16rtn(r[1]), w2 = bf16rtn(r[2]);
            unsigned w3 = bf16rtn(r[3]), w4 = bf16rtn(r[4]);
            uint4 o;
            o.x = w0 | (w1 << 16);
            o.y = w2 | (w3 << 16);
            o.z = w4;
            o.w = 0u;
            fp[i] = o;
        }
    }
}

// P3: k5(A) || hist(B)
__global__ __launch_bounds__(BLK) void g_k5k2(const int* __restrict__ src,
                                              const int* __restrict__ dst,
                                              const unsigned short* __restrict__ bhA,
                                              const int* __restrict__ bbaseA,
                                              int* __restrict__ bdata,
                                              unsigned short* __restrict__ bhB,
                                              int chunk, int half) {
    __shared__ int u[NB];
    int bid = blockIdx.x;
    if (bid < NSBH) k5_body(bid, src, dst, bhA, bbaseA, bdata, chunk, u);
    else            k2_body(bid - NSBH, dst + half, bhB, chunk, u);
}

// P5: k5(B) || k6(A)  — measures read-wall vs scatter-write independence
__global__ __launch_bounds__(BLK) void g_k6k5(const int* __restrict__ src,
                                              const int* __restrict__ dst,
                                              const unsigned short* __restrict__ bhB,
                                              const int* __restrict__ bbaseB,
                                              int* __restrict__ bdata,
                                              const uint4* __restrict__ fp,
                                              const int* __restrict__ bbaseA,
                                              const int* __restrict__ btotA,
                                              float* __restrict__ out,
                                              int chunk, int half) {
    __shared__ int u[NB];
    int bid = blockIdx.x;
    if (bid < NSBH)
        k5_body(bid, src + half, dst + half, bhB, bbaseB, bdata + half, chunk, u);
    else
        k6_body(bid - NSBH, bdata, fp, bbaseA, btotA, out, false, (float*)u);
}

// P6: k6(B), accumulating onto k6(A)'s stores
__global__ __launch_bounds__(BLK) void g_k6(const int* __restrict__ bdata,
                                            const uint4* __restrict__ fp,
                                            const int* __restrict__ bbaseB,
                                            const int* __restrict__ btotB,
                                            float* __restrict__ out, int half) {
    __shared__ float acc[NPS * FD];
    k6_body(blockIdx.x, bdata + half, fp, bbaseB, btotB, out, true, acc);
}

// ---------- Fallback: direct global atomics ---------------------------------
__global__ void scatter_add_fallback(const float* __restrict__ features,
                                     const int* __restrict__ src,
                                     const int* __restrict__ dst,
                                     float* __restrict__ out, int n_edges) {
    int idx = blockIdx.x * blockDim.x + threadIdx.x;
    int stride = gridDim.x * blockDim.x;
    for (int e = idx; e < n_edges; e += stride) {
        int u = src[e], v = dst[e];
        const float* f = features + (long long)u * FD;
        float* o = out + (long long)v * FD;
#pragma unroll
        for (int k = 0; k < FD; ++k) atomicAdd(&o[k], f[k]);
    }
}

extern "C" void kernel_launch(void* const* d_in, const int* in_sizes, int n_in,
                              void* d_out, int out_size, void* d_ws, size_t ws_size,
                              hipStream_t stream) {
    const float* features = (const float*)d_in[0];
    const int*   src      = (const int*)d_in[1];
    const int*   dst      = (const int*)d_in[2];
    float* out = (float*)d_out;
    int n_edges = in_sizes[1];

    // ws carve. Region1 holds bhA (dead after P3) then fpad (written P4).
    size_t o_bd  = 0;                                        // bdata: E*4
    size_t o_r1  = o_bd + (size_t)n_edges * 4 + 64;          // bhA | fpad
    size_t sz_r1 = (size_t)NSBH * NB * 2;                    // 2.5 MB
    size_t sz_fp = (size_t)NN * sizeof(uint4);               // 1.6 MB
    if (sz_fp > sz_r1) sz_r1 = sz_fp;
    size_t o_bhB = o_r1 + ((sz_r1 + 15) & ~(size_t)15);      // bhB: 2.5 MB
    size_t o_bbA = o_bhB + (((size_t)NSBH * NB * 2 + 15) & ~(size_t)15);
    size_t o_btA = o_bbA + (size_t)NB * 4;
    size_t o_bbB = o_btA + (size_t)NB * 4;
    size_t o_btB = o_bbB + (size_t)NB * 4;
    size_t need  = o_btB + (size_t)NB * 4;

    bool fast = (out_size == NOUTT) && (in_sizes[0] == NOUTT) &&
                (n_edges % (2 * NSBH * 4) == 0) && (need <= ws_size);

    if (fast) {
        char* w = (char*)d_ws;
        int*            bdata = (int*)(w + o_bd);
        unsigned short* bhA   = (unsigned short*)(w + o_r1);
        uint4*          fpad  = (uint4*)(w + o_r1);          // aliases bhA (safe)
        unsigned short* bhB   = (unsigned short*)(w + o_bhB);
        int*            bbaseA = (int*)(w + o_bbA);
        int*            btotA  = (int*)(w + o_btA);
        int*            bbaseB = (int*)(w + o_bbB);
        int*            btotB  = (int*)(w + o_btB);
        int half  = n_edges / 2;
        int chunk = half / NSBH;   // 8000, divisible by 4

        g_k2  <<<NSBH, BLK, 0, stream>>>(dst, bhA, chunk);                 // histA
        g_k3  <<<NB,   BLK, 0, stream>>>(bhA, btotA);                      // scanA
        g_k4  <<<1,    BLK, 0, stream>>>(btotA, bbaseA);
        g_k5k2<<<2 * NSBH, BLK, 0, stream>>>(src, dst, bhA, bbaseA,        // k5A||histB
                                             bdata, bhB, chunk, half);
        g_k3  <<<NB,   BLK, 0, stream>>>(bhB, btotB);                      // scanB
        g_k4k1<<<1 + (NN + BLK - 1) / BLK, BLK, 0, stream>>>(btotB, bbaseB,
                                                             features, fpad);
        g_k6k5<<<NSBH + NB, BLK, 0, stream>>>(src, dst, bhB, bbaseB, bdata,
                                              fpad, bbaseA, btotA, out,
                                              chunk, half);                // k6A||k5B
        g_k6  <<<NB,   BLK, 0, stream>>>(bdata, fpad, bbaseB, btotB, out, half);
    } else {
        (void)hipMemsetAsync(d_out, 0, (size_t)out_size * sizeof(float), stream);
        int grid = (n_edges + BLK - 1) / BLK;
        if (grid > 65535) grid = 65535;
        scatter_add_fallback<<<grid, BLK, 0, stream>>>(features, src, dst, out, n_edges);
    }
}